// Round 9
// baseline (7848.364 us; speedup 1.0000x reference)
//
#include <hip/hip_runtime.h>
#include <math.h>

#define F_FRAMES 1021
#define BATCH 16
#define T_LEN 262144
#define FREQn 513
#define HID 128
#define ENCn 256
#define BF (BATCH * F_FRAMES)  // 16336

typedef float v4f __attribute__((ext_vector_type(4)));
typedef _Float16 f16x8 __attribute__((ext_vector_type(8)));
typedef _Float16 f16x4 __attribute__((ext_vector_type(4)));

__device__ __forceinline__ float sigmoidf_(float x) {
  return 1.f / (1.f + __expf(-x));
}
__device__ __forceinline__ float tanhf_(float x) {
  return 1.f - 2.f / (__expf(2.f * x) + 1.f);
}

// ---------------- STFT: frame + window + rfft(1024) -> mag, cos(phase), sin(phase)
__global__ __launch_bounds__(256) void stft_kernel(
    const float* __restrict__ x, float* __restrict__ mag,
    float* __restrict__ cosp, float* __restrict__ sinp) {
  __shared__ float zr[512], zi[512];
  int bf = blockIdx.x;
  int b = bf / F_FRAMES;
  int f = bf - b * F_FRAMES;
  const float* xb = x + (size_t)b * T_LEN + (size_t)f * 256;
  int tid = threadIdx.x;
  const float wstep = 6.28318530717958647692f / 1024.f;
#pragma unroll
  for (int u = 0; u < 2; ++u) {
    int j = tid + u * 256;
    int n = __brev((unsigned)j) >> 23;  // 9-bit bit-reverse
    float x0 = xb[2 * n] * (0.5f - 0.5f * __cosf((float)(2 * n) * wstep));
    float x1 = xb[2 * n + 1] * (0.5f - 0.5f * __cosf((float)(2 * n + 1) * wstep));
    zr[j] = x0;
    zi[j] = x1;
  }
  __syncthreads();
#pragma unroll
  for (int s = 1; s <= 9; ++s) {
    int half = 1 << (s - 1);
    int t = tid & (half - 1);
    int g = tid >> (s - 1);
    int pos = (g << s) + t;
    float ang = (float)t * (3.14159265358979323846f / (float)half);
    float sn, cs;
    __sincosf(ang, &sn, &cs);
    float wr = cs, wi = -sn;
    float ar = zr[pos], ai = zi[pos];
    float br = zr[pos + half], bi = zi[pos + half];
    float tr = wr * br - wi * bi;
    float ti = wr * bi + wi * br;
    zr[pos] = ar + tr;
    zi[pos] = ai + ti;
    zr[pos + half] = ar - tr;
    zi[pos + half] = ai - ti;
    __syncthreads();
  }
  const float eps = 1.1920928955078125e-07f;
  for (int k = tid; k < 513; k += 256) {
    int ka = k & 511;
    int kb = (512 - k) & 511;
    float zar = zr[ka], zai = zi[ka];
    float zbr = zr[kb], zbi = zi[kb];
    float Zer = 0.5f * (zar + zbr);
    float Zei = 0.5f * (zai - zbi);
    float Zor = 0.5f * (zai + zbi);
    float Zoi = -0.5f * (zar - zbr);
    float ang = (float)k * (3.14159265358979323846f / 512.f);
    float sn, cs;
    __sincosf(ang, &sn, &cs);
    float Wr = cs, Wi = -sn;
    float re = Zer + Wr * Zor - Wi * Zoi;
    float im = Zei + Wr * Zoi + Wi * Zor;
    size_t idx = (size_t)bf * FREQn + k;
    float p2 = re * re + im * im;
    mag[idx] = sqrtf(fmaxf(p2, eps));
    float rr = re + eps, ii = im + eps;
    float inv = rsqrtf(rr * rr + ii * ii);
    cosp[idx] = rr * inv;
    sinp[idx] = ii * inv;
  }
}

// ---------------- iSTFT: est spectrum -> irfft(1024) frames
__global__ __launch_bounds__(256) void istft_kernel(
    const float* __restrict__ er, const float* __restrict__ ei,
    float* __restrict__ y) {
  __shared__ float xr[513], xi[513];
  __shared__ float zr[512], zi[512];
  int bf = blockIdx.x;
  int tid = threadIdx.x;
  for (int k = tid; k < 513; k += 256) {
    size_t idx = (size_t)bf * FREQn + k;
    xr[k] = er[idx];
    float v = ei[idx];
    xi[k] = (k == 0 || k == 512) ? 0.f : v;  // pocketfft c2r ignores DC/Nyquist imag
  }
  __syncthreads();
#pragma unroll
  for (int u = 0; u < 2; ++u) {
    int k = tid + u * 256;  // 0..511
    int kk = 512 - k;
    float Xkr = xr[k], Xki = xi[k];
    float Xbr = xr[kk], Xbi = xi[kk];
    float Zer = 0.5f * (Xkr + Xbr);
    float Zei = 0.5f * (Xki - Xbi);
    float Vr = 0.5f * (Xkr - Xbr);
    float Vi = 0.5f * (Xki + Xbi);
    float ang = (float)k * (3.14159265358979323846f / 512.f);
    float sn, cs;
    __sincosf(ang, &sn, &cs);
    float Zor = cs * Vr - sn * Vi;  // e^{+i pi k/512} * V
    float Zoi = cs * Vi + sn * Vr;
    float Rr = Zer - Zoi;  // Z = Ze + i*Zo
    float Ri = Zei + Zor;
    int d = __brev((unsigned)k) >> 23;
    zr[d] = Rr;
    zi[d] = Ri;
  }
  __syncthreads();
#pragma unroll
  for (int s = 1; s <= 9; ++s) {
    int half = 1 << (s - 1);
    int t = tid & (half - 1);
    int g = tid >> (s - 1);
    int pos = (g << s) + t;
    float ang = (float)t * (3.14159265358979323846f / (float)half);
    float sn, cs;
    __sincosf(ang, &sn, &cs);
    float wr = cs, wi = sn;  // conjugate twiddles => unnormalized IDFT
    float ar = zr[pos], ai = zi[pos];
    float br = zr[pos + half], bi = zi[pos + half];
    float tr = wr * br - wi * bi;
    float ti = wr * bi + wi * br;
    zr[pos] = ar + tr;
    zi[pos] = ai + ti;
    zr[pos + half] = ar - tr;
    zi[pos + half] = ai - ti;
    __syncthreads();
  }
  const float sc = 1.f / 512.f;
  float2* y2 = (float2*)(y + (size_t)bf * 1024);
#pragma unroll
  for (int u = 0; u < 2; ++u) {
    int n = tid + u * 256;
    y2[n] = make_float2(zr[n] * sc, zi[n] * sc);
  }
}

// ---------------- generic fp32 GEMM: C[M,N] = A[M,K] @ W[N,K]^T (+bias)(+epilogue)
template <int MODE>
__global__ __launch_bounds__(256) void gemm_nt(
    const float* __restrict__ A, const float* __restrict__ W,
    const float* __restrict__ bias, float* __restrict__ C, int M, int N, int K,
    const float* __restrict__ aux1, float* __restrict__ aux2,
    float* __restrict__ aux3) {
  __shared__ float As[16][68];
  __shared__ float Ws[16][68];
  int tid = threadIdx.x;
  int tx = tid & 15, ty = tid >> 4;
  int m0 = blockIdx.y * 64, n0 = blockIdx.x * 64;
  float acc[4][4] = {};
  int klc = tid & 15;
  int rl = tid >> 4;
  for (int k0 = 0; k0 < K; k0 += 16) {
#pragma unroll
    for (int r = 0; r < 4; ++r) {
      int row = rl + r * 16;
      int m = m0 + row;
      int k = k0 + klc;
      As[klc][row] = (m < M && k < K) ? A[(size_t)m * K + k] : 0.f;
      int n = n0 + row;
      Ws[klc][row] = (n < N && k < K) ? W[(size_t)n * K + k] : 0.f;
    }
    __syncthreads();
#pragma unroll
    for (int kk = 0; kk < 16; ++kk) {
      float4 a4 = *reinterpret_cast<const float4*>(&As[kk][ty * 4]);
      float4 w4 = *reinterpret_cast<const float4*>(&Ws[kk][tx * 4]);
      float av[4] = {a4.x, a4.y, a4.z, a4.w};
      float wv[4] = {w4.x, w4.y, w4.z, w4.w};
#pragma unroll
      for (int i = 0; i < 4; ++i)
#pragma unroll
        for (int j = 0; j < 4; ++j)
          acc[i][j] = fmaf(av[i], wv[j], acc[i][j]);
    }
    __syncthreads();
  }
#pragma unroll
  for (int i = 0; i < 4; ++i) {
    int m = m0 + ty * 4 + i;
    if (m >= M) continue;
#pragma unroll
    for (int j = 0; j < 4; ++j) {
      int n = n0 + tx * 4 + j;
      if (n >= N) continue;
      float v = acc[i][j];
      if (bias) v += bias[n];
      size_t idx = (size_t)m * N + n;
      if (MODE == 0) {
        C[idx] = v;
      } else if (MODE == 1) {
        float s = sigmoidf_(v);
        float em = s * aux1[idx];
        aux2[idx] = em * aux2[idx];
        aux3[idx] = em * aux3[idx];
      } else {
        float s = sigmoidf_(v);
        C[idx] = s * aux1[idx];
      }
    }
  }
}

// ---------------- prep: pack Whh (4 matrices) into f16 hi/lo MFMA A-fragments
// layout [mat 4][wave 8][gate 3][ktile 4][prec 2][lane 64][j 8] _Float16
// A-frag of mfma_f32_16x16x32_f16: lane l holds A[row = l&15][k = (l>>4)*8 + j]
__global__ __launch_bounds__(256) void prep_wfrag(
    const float* __restrict__ W0, const float* __restrict__ W1,
    const float* __restrict__ W2, const float* __restrict__ W3,
    _Float16* __restrict__ out) {
  int idx = blockIdx.x * 256 + threadIdx.x;
  if (idx >= 4 * 98304) return;
  int j = idx & 7;
  int lane = (idx >> 3) & 63;
  int prec = (idx >> 9) & 1;
  int k = (idx >> 10) & 3;
  int rest = idx >> 12;  // 0..95 = [mat][w][g]
  int mat = rest / 24;
  int wg = rest % 24;
  int w = wg / 3, g = wg % 3;
  const float* W = mat == 0 ? W0 : mat == 1 ? W1 : mat == 2 ? W2 : W3;
  int row = g * 128 + w * 16 + (lane & 15);
  int col = k * 32 + (lane >> 4) * 8 + j;
  float v = W[row * 128 + col];
  _Float16 hi = (_Float16)v;
  out[idx] = prec ? (_Float16)(v - (float)hi) : hi;
}

// ---------------- MFMA GRU scan: ONE block, all 16 batches as N=16.
// Whh lives in MFMA A-fragments (f16 hi/lo, 2-term for ~fp32 weight precision);
// h state: f16 in LDS (B-operand), exact fp32 in lane registers for the z*h term.
// Per step: 24 MFMA/wave + 4 ds_read_b128/wave + gates + 1 barrier.
__global__ __launch_bounds__(512, 2)
__attribute__((amdgpu_waves_per_eu(2, 2))) void gru_scan_mfma(
    const float* __restrict__ xg,    // [B, F, 384]
    const _Float16* __restrict__ wf, // this GRU's fragment pack
    const float* __restrict__ bhh,   // [384]
    const float* __restrict__ h0,    // [B, 128]
    float* __restrict__ hout,        // [B, F, 128]
    float* __restrict__ hlast,       // [B, 128]
    int F) {
  __shared__ __align__(16) _Float16 HT[2][16][136];  // [buf][batch][k(128)+pad8]
  int tid = threadIdx.x;
  int wv = tid >> 6, l = tid & 63;
  int n = l & 15;       // batch (C col / B col)
  int rq = l >> 4;      // row-quad (C rows rq*4..rq*4+3 within tile)
  int rbase = wv * 16 + rq * 4;  // absolute h-row base (0..124)

  // A-fragments: gate g, K-tile k, hi/lo
  f16x8 whi[3][4], wlo[3][4];
  const f16x8* fb = (const f16x8*)wf;
#pragma unroll
  for (int g = 0; g < 3; ++g)
#pragma unroll
    for (int k = 0; k < 4; ++k) {
      whi[g][k] = fb[(((wv * 3 + g) * 4 + k) * 2 + 0) * 64 + l];
      wlo[g][k] = fb[(((wv * 3 + g) * 4 + k) * 2 + 1) * 64 + l];
    }
  float bhr[4], bhz[4], bhn[4];
#pragma unroll
  for (int r = 0; r < 4; ++r) {
    bhr[r] = bhh[rbase + r];
    bhz[r] = bhh[128 + rbase + r];
    bhn[r] = bhh[256 + rbase + r];
  }
  float hp[4];
#pragma unroll
  for (int r = 0; r < 4; ++r) {
    hp[r] = h0[n * 128 + rbase + r];
    HT[0][n][rbase + r] = (_Float16)hp[r];
  }
  const float* xp = xg + ((size_t)n * F) * 384 + rbase;
  float* hq = hout + ((size_t)n * F) * 128 + rbase;
  // xg prefetch ring: slots for t (a) and t+1 (b)
  v4f xra = *(const v4f*)(xp);
  v4f xza = *(const v4f*)(xp + 128);
  v4f xna = *(const v4f*)(xp + 256);
  const float* p1 = xp + (size_t)(F > 1 ? 1 : 0) * 384;
  v4f xrb = *(const v4f*)(p1);
  v4f xzb = *(const v4f*)(p1 + 128);
  v4f xnb = *(const v4f*)(p1 + 256);
  __syncthreads();

  int cur = 0;
  for (int t = 0; t < F; ++t) {
    // B-fragments: lane reads k = ktile*32 + rq*8 + j, batch n
    const _Float16* hrow = &HT[cur][n][0];
    f16x8 b0 = *(const f16x8*)(hrow + rq * 8);
    f16x8 b1 = *(const f16x8*)(hrow + 32 + rq * 8);
    f16x8 b2 = *(const f16x8*)(hrow + 64 + rq * 8);
    f16x8 b3 = *(const f16x8*)(hrow + 96 + rq * 8);
    // consume ring slot a, rotate, prefetch t+2
    v4f xr = xra, xz = xza, xn = xna;
    xra = xrb; xza = xzb; xna = xnb;
    {
      int tp = (t + 2 < F) ? t + 2 : F - 1;
      const float* p2 = xp + (size_t)tp * 384;
      xrb = *(const v4f*)(p2);
      xzb = *(const v4f*)(p2 + 128);
      xnb = *(const v4f*)(p2 + 256);
    }
    v4f ar = {0.f, 0.f, 0.f, 0.f}, az = ar, an = ar;
#pragma unroll
    for (int k = 0; k < 4; ++k) {
      f16x8 bk = (k == 0) ? b0 : (k == 1) ? b1 : (k == 2) ? b2 : b3;
      ar = __builtin_amdgcn_mfma_f32_16x16x32_f16(whi[0][k], bk, ar, 0, 0, 0);
      az = __builtin_amdgcn_mfma_f32_16x16x32_f16(whi[1][k], bk, az, 0, 0, 0);
      an = __builtin_amdgcn_mfma_f32_16x16x32_f16(whi[2][k], bk, an, 0, 0, 0);
      ar = __builtin_amdgcn_mfma_f32_16x16x32_f16(wlo[0][k], bk, ar, 0, 0, 0);
      az = __builtin_amdgcn_mfma_f32_16x16x32_f16(wlo[1][k], bk, az, 0, 0, 0);
      an = __builtin_amdgcn_mfma_f32_16x16x32_f16(wlo[2][k], bk, an, 0, 0, 0);
    }
    int nxt = cur ^ 1;
    f16x4 hv;
    v4f ho;
#pragma unroll
    for (int r = 0; r < 4; ++r) {
      float rr = sigmoidf_(ar[r] + bhr[r] + xr[r]);
      float zz = sigmoidf_(az[r] + bhz[r] + xz[r]);
      float gn = an[r] + bhn[r];
      float nv = tanhf_(xn[r] + rr * gn);
      float hn = (1.f - zz) * nv + zz * hp[r];
      hp[r] = hn;
      hv[r] = (_Float16)hn;
      ho[r] = hn;
    }
    *(f16x4*)&HT[nxt][n][rbase] = hv;
    *(v4f*)(hq + (size_t)t * 128) = ho;
    __syncthreads();  // writes of HT[nxt] complete; reads of HT[cur] were all
                      // before this barrier -> next iter reads nxt, writes cur
    cur = nxt;
  }
#pragma unroll
  for (int r = 0; r < 4; ++r) hlast[n * 128 + rbase + r] = hp[r];
}

// ---------------- instant layernorm over channels (256)
__global__ __launch_bounds__(256) void ln_kernel(
    const float* __restrict__ enc, const float* __restrict__ gamma,
    const float* __restrict__ beta, float* __restrict__ out) {
  int row = blockIdx.x * 4 + (threadIdx.x >> 6);
  int lane = threadIdx.x & 63;
  const float* p = enc + (size_t)row * ENCn;
  float4 v = *reinterpret_cast<const float4*>(p + lane * 4);
  float s = v.x + v.y + v.z + v.w;
  float ss = v.x * v.x + v.y * v.y + v.z * v.z + v.w * v.w;
#pragma unroll
  for (int o = 32; o > 0; o >>= 1) {
    s += __shfl_down(s, o);
    ss += __shfl_down(ss, o);
  }
  s = __shfl(s, 0);
  ss = __shfl(ss, 0);
  float mean = s * (1.f / 256.f);
  float var = ss * (1.f / 256.f) - mean * mean;
  float rstd = rsqrtf(var + 1e-7f);
  float4 g4 = *reinterpret_cast<const float4*>(gamma + lane * 4);
  float4 b4 = *reinterpret_cast<const float4*>(beta + lane * 4);
  float4 o4;
  o4.x = (v.x - mean) * rstd * g4.x + b4.x;
  o4.y = (v.y - mean) * rstd * g4.y + b4.y;
  o4.z = (v.z - mean) * rstd * g4.z + b4.z;
  o4.w = (v.w - mean) * rstd * g4.w + b4.w;
  *reinterpret_cast<float4*>(out + (size_t)row * ENCn + lane * 4) = o4;
}

// ---------------- overlap-add
__global__ __launch_bounds__(256) void ola_kernel(const float* __restrict__ dec,
                                                  float* __restrict__ out) {
  int idx = blockIdx.x * 256 + threadIdx.x;  // b*T + n
  int b = idx >> 18;                          // T = 2^18
  int n = idx & (T_LEN - 1);
  int f0 = (n < 768) ? 0 : ((n - 768) >> 8);
  int f1 = min(n >> 8, F_FRAMES - 1);
  float s = 0.f;
  for (int f = f0; f <= f1; ++f)
    s += dec[((size_t)b * F_FRAMES + f) * 1024 + (n - (f << 8))];
  out[idx] = s;
}

extern "C" void kernel_launch(void* const* d_in, const int* in_sizes, int n_in,
                              void* d_out, int out_size, void* d_ws,
                              size_t ws_size, hipStream_t stream) {
  const float* x = (const float*)d_in[0];
  const float* in_st1 = (const float*)d_in[1];
  const float* in_st2 = (const float*)d_in[2];
  const float* s1_Wih1 = (const float*)d_in[3];
  const float* s1_Whh1 = (const float*)d_in[4];
  const float* s1_bih1 = (const float*)d_in[5];
  const float* s1_bhh1 = (const float*)d_in[6];
  const float* s1_Wih2 = (const float*)d_in[7];
  const float* s1_Whh2 = (const float*)d_in[8];
  const float* s1_bih2 = (const float*)d_in[9];
  const float* s1_bhh2 = (const float*)d_in[10];
  const float* s1_Wd = (const float*)d_in[11];
  const float* s1_bd = (const float*)d_in[12];
  const float* enc_W = (const float*)d_in[13];
  const float* gamma = (const float*)d_in[14];
  const float* beta = (const float*)d_in[15];
  const float* s2_Wih1 = (const float*)d_in[16];
  const float* s2_Whh1 = (const float*)d_in[17];
  const float* s2_bih1 = (const float*)d_in[18];
  const float* s2_bhh1 = (const float*)d_in[19];
  const float* s2_Wih2 = (const float*)d_in[20];
  const float* s2_Whh2 = (const float*)d_in[21];
  const float* s2_bih2 = (const float*)d_in[22];
  const float* s2_bhh2 = (const float*)d_in[23];
  const float* s2_Wd = (const float*)d_in[24];
  const float* s2_bd = (const float*)d_in[25];
  const float* dec_W = (const float*)d_in[26];

  float* out = (float*)d_out;
  float* st_out = out + (size_t)BATCH * T_LEN;  // [2,16,128] + [2,16,128]

  float* ws = (float*)d_ws;
  float* mag = ws;                              // BF*513
  float* cosp = mag + (size_t)BF * FREQn;       // BF*513 (-> est_re)
  float* sinp = cosp + (size_t)BF * FREQn;      // BF*513 (-> est_im)
  float* xg = sinp + (size_t)BF * FREQn;        // BF*384 (shared A/B gate buf)
  float* h1 = xg + (size_t)BF * 384;            // BF*128
  float* h2 = h1 + (size_t)BF * HID;            // BF*128
  float* ybuf = h2 + (size_t)BF * HID;          // BF*1024 (y1, then dec)
  float* enc = ybuf + (size_t)BF * 1024;        // BF*256
  float* encn = enc + (size_t)BF * ENCn;        // BF*256 (enc_norm, then est2)
  _Float16* wfrag = (_Float16*)(encn + (size_t)BF * ENCn);  // 4*98304 f16

  auto gg = [](int M, int N) { return dim3((N + 63) / 64, (M + 63) / 64); };

  // 0. pack all four Whh into MFMA fragment order (f16 hi/lo)
  prep_wfrag<<<1536, 256, 0, stream>>>(s1_Whh1, s1_Whh2, s2_Whh1, s2_Whh2,
                                       wfrag);
  // 1. STFT -> mag, cos, sin
  stft_kernel<<<BF, 256, 0, stream>>>(x, mag, cosp, sinp);
  // 2. sep1 GRU-a input gates
  gemm_nt<0><<<gg(BF, 384), 256, 0, stream>>>(mag, s1_Wih1, s1_bih1, xg, BF,
                                              384, FREQn, nullptr, nullptr,
                                              nullptr);
  // 3. scan a
  gru_scan_mfma<<<1, 512, 0, stream>>>(xg, wfrag + 0 * 98304, s1_bhh1, in_st1,
                                       h1, st_out, F_FRAMES);
  // 4. sep1 GRU-b input gates (xg consumed by step 3 -> reuse)
  gemm_nt<0><<<gg(BF, 384), 256, 0, stream>>>(h1, s1_Wih2, s1_bih2, xg, BF,
                                              384, HID, nullptr, nullptr,
                                              nullptr);
  // 5. scan b
  gru_scan_mfma<<<1, 512, 0, stream>>>(xg, wfrag + 1 * 98304, s1_bhh2,
                                       in_st1 + 2048, h2, st_out + 2048,
                                       F_FRAMES);
  // 6. mask1 dense + est spectrum (overwrites cosp/sinp)
  gemm_nt<1><<<gg(BF, FREQn), 256, 0, stream>>>(h2, s1_Wd, s1_bd, nullptr, BF,
                                                FREQn, HID, mag, cosp, sinp);
  // 7. iSTFT -> y1
  istft_kernel<<<BF, 256, 0, stream>>>(cosp, sinp, ybuf);
  // 8. encoder
  gemm_nt<0><<<gg(BF, ENCn), 256, 0, stream>>>(ybuf, enc_W, nullptr, enc, BF,
                                               ENCn, 1024, nullptr, nullptr,
                                               nullptr);
  // 9. instant LN
  ln_kernel<<<BF / 4, 256, 0, stream>>>(enc, gamma, beta, encn);
  // 10. sep2 GRU-a input gates
  gemm_nt<0><<<gg(BF, 384), 256, 0, stream>>>(encn, s2_Wih1, s2_bih1, xg, BF,
                                              384, ENCn, nullptr, nullptr,
                                              nullptr);
  // 11. scan 2a
  gru_scan_mfma<<<1, 512, 0, stream>>>(xg, wfrag + 2 * 98304, s2_bhh1, in_st2,
                                       h1, st_out + 4096, F_FRAMES);
  // 12. sep2 GRU-b input gates
  gemm_nt<0><<<gg(BF, 384), 256, 0, stream>>>(h1, s2_Wih2, s2_bih2, xg, BF,
                                              384, HID, nullptr, nullptr,
                                              nullptr);
  // 13. scan 2b
  gru_scan_mfma<<<1, 512, 0, stream>>>(xg, wfrag + 3 * 98304, s2_bhh2,
                                       in_st2 + 2048, h2, st_out + 6144,
                                       F_FRAMES);
  // 14. mask2 -> est2 (reads enc, writes encn)
  gemm_nt<2><<<gg(BF, ENCn), 256, 0, stream>>>(h2, s2_Wd, s2_bd, encn, BF,
                                               ENCn, HID, enc, nullptr,
                                               nullptr);
  // 15. decoder (reuses ybuf)
  gemm_nt<0><<<gg(BF, 1024), 256, 0, stream>>>(encn, dec_W, nullptr, ybuf, BF,
                                               1024, ENCn, nullptr, nullptr,
                                               nullptr);
  // 16. overlap-add
  ola_kernel<<<(BATCH * T_LEN) / 256, 256, 0, stream>>>(ybuf, out);
}

// Round 10
// 5444.678 us; speedup vs baseline: 1.4415x; 1.4415x over previous
//
#include <hip/hip_runtime.h>
#include <math.h>

#define F_FRAMES 1021
#define BATCH 16
#define T_LEN 262144
#define FREQn 513
#define HID 128
#define ENCn 256
#define BF (BATCH * F_FRAMES)  // 16336

typedef float v4f __attribute__((ext_vector_type(4)));
typedef _Float16 f16x8 __attribute__((ext_vector_type(8)));
typedef _Float16 f16x4 __attribute__((ext_vector_type(4)));

__device__ __forceinline__ float sigmoidf_(float x) {
  return 1.f / (1.f + __expf(-x));
}
__device__ __forceinline__ float tanhf_(float x) {
  return 1.f - 2.f / (__expf(2.f * x) + 1.f);
}

// ---------------- STFT: frame + window + rfft(1024) -> mag, cos(phase), sin(phase)
__global__ __launch_bounds__(256) void stft_kernel(
    const float* __restrict__ x, float* __restrict__ mag,
    float* __restrict__ cosp, float* __restrict__ sinp) {
  __shared__ float zr[512], zi[512];
  int bf = blockIdx.x;
  int b = bf / F_FRAMES;
  int f = bf - b * F_FRAMES;
  const float* xb = x + (size_t)b * T_LEN + (size_t)f * 256;
  int tid = threadIdx.x;
  const float wstep = 6.28318530717958647692f / 1024.f;
#pragma unroll
  for (int u = 0; u < 2; ++u) {
    int j = tid + u * 256;
    int n = __brev((unsigned)j) >> 23;  // 9-bit bit-reverse
    float x0 = xb[2 * n] * (0.5f - 0.5f * __cosf((float)(2 * n) * wstep));
    float x1 = xb[2 * n + 1] * (0.5f - 0.5f * __cosf((float)(2 * n + 1) * wstep));
    zr[j] = x0;
    zi[j] = x1;
  }
  __syncthreads();
#pragma unroll
  for (int s = 1; s <= 9; ++s) {
    int half = 1 << (s - 1);
    int t = tid & (half - 1);
    int g = tid >> (s - 1);
    int pos = (g << s) + t;
    float ang = (float)t * (3.14159265358979323846f / (float)half);
    float sn, cs;
    __sincosf(ang, &sn, &cs);
    float wr = cs, wi = -sn;
    float ar = zr[pos], ai = zi[pos];
    float br = zr[pos + half], bi = zi[pos + half];
    float tr = wr * br - wi * bi;
    float ti = wr * bi + wi * br;
    zr[pos] = ar + tr;
    zi[pos] = ai + ti;
    zr[pos + half] = ar - tr;
    zi[pos + half] = ai - ti;
    __syncthreads();
  }
  const float eps = 1.1920928955078125e-07f;
  for (int k = tid; k < 513; k += 256) {
    int ka = k & 511;
    int kb = (512 - k) & 511;
    float zar = zr[ka], zai = zi[ka];
    float zbr = zr[kb], zbi = zi[kb];
    float Zer = 0.5f * (zar + zbr);
    float Zei = 0.5f * (zai - zbi);
    float Zor = 0.5f * (zai + zbi);
    float Zoi = -0.5f * (zar - zbr);
    float ang = (float)k * (3.14159265358979323846f / 512.f);
    float sn, cs;
    __sincosf(ang, &sn, &cs);
    float Wr = cs, Wi = -sn;
    float re = Zer + Wr * Zor - Wi * Zoi;
    float im = Zei + Wr * Zoi + Wi * Zor;
    size_t idx = (size_t)bf * FREQn + k;
    float p2 = re * re + im * im;
    mag[idx] = sqrtf(fmaxf(p2, eps));
    float rr = re + eps, ii = im + eps;
    float inv = rsqrtf(rr * rr + ii * ii);
    cosp[idx] = rr * inv;
    sinp[idx] = ii * inv;
  }
}

// ---------------- iSTFT: est spectrum -> irfft(1024) frames
__global__ __launch_bounds__(256) void istft_kernel(
    const float* __restrict__ er, const float* __restrict__ ei,
    float* __restrict__ y) {
  __shared__ float xr[513], xi[513];
  __shared__ float zr[512], zi[512];
  int bf = blockIdx.x;
  int tid = threadIdx.x;
  for (int k = tid; k < 513; k += 256) {
    size_t idx = (size_t)bf * FREQn + k;
    xr[k] = er[idx];
    float v = ei[idx];
    xi[k] = (k == 0 || k == 512) ? 0.f : v;  // pocketfft c2r ignores DC/Nyquist imag
  }
  __syncthreads();
#pragma unroll
  for (int u = 0; u < 2; ++u) {
    int k = tid + u * 256;  // 0..511
    int kk = 512 - k;
    float Xkr = xr[k], Xki = xi[k];
    float Xbr = xr[kk], Xbi = xi[kk];
    float Zer = 0.5f * (Xkr + Xbr);
    float Zei = 0.5f * (Xki - Xbi);
    float Vr = 0.5f * (Xkr - Xbr);
    float Vi = 0.5f * (Xki + Xbi);
    float ang = (float)k * (3.14159265358979323846f / 512.f);
    float sn, cs;
    __sincosf(ang, &sn, &cs);
    float Zor = cs * Vr - sn * Vi;  // e^{+i pi k/512} * V
    float Zoi = cs * Vi + sn * Vr;
    float Rr = Zer - Zoi;  // Z = Ze + i*Zo
    float Ri = Zei + Zor;
    int d = __brev((unsigned)k) >> 23;
    zr[d] = Rr;
    zi[d] = Ri;
  }
  __syncthreads();
#pragma unroll
  for (int s = 1; s <= 9; ++s) {
    int half = 1 << (s - 1);
    int t = tid & (half - 1);
    int g = tid >> (s - 1);
    int pos = (g << s) + t;
    float ang = (float)t * (3.14159265358979323846f / (float)half);
    float sn, cs;
    __sincosf(ang, &sn, &cs);
    float wr = cs, wi = sn;  // conjugate twiddles => unnormalized IDFT
    float ar = zr[pos], ai = zi[pos];
    float br = zr[pos + half], bi = zi[pos + half];
    float tr = wr * br - wi * bi;
    float ti = wr * bi + wi * br;
    zr[pos] = ar + tr;
    zi[pos] = ai + ti;
    zr[pos + half] = ar - tr;
    zi[pos + half] = ai - ti;
    __syncthreads();
  }
  const float sc = 1.f / 512.f;
  float2* y2 = (float2*)(y + (size_t)bf * 1024);
#pragma unroll
  for (int u = 0; u < 2; ++u) {
    int n = tid + u * 256;
    y2[n] = make_float2(zr[n] * sc, zi[n] * sc);
  }
}

// ---------------- generic fp32 GEMM: C[M,N] = A[M,K] @ W[N,K]^T (+bias)(+epilogue)
template <int MODE>
__global__ __launch_bounds__(256) void gemm_nt(
    const float* __restrict__ A, const float* __restrict__ W,
    const float* __restrict__ bias, float* __restrict__ C, int M, int N, int K,
    const float* __restrict__ aux1, float* __restrict__ aux2,
    float* __restrict__ aux3) {
  __shared__ float As[16][68];
  __shared__ float Ws[16][68];
  int tid = threadIdx.x;
  int tx = tid & 15, ty = tid >> 4;
  int m0 = blockIdx.y * 64, n0 = blockIdx.x * 64;
  float acc[4][4] = {};
  int klc = tid & 15;
  int rl = tid >> 4;
  for (int k0 = 0; k0 < K; k0 += 16) {
#pragma unroll
    for (int r = 0; r < 4; ++r) {
      int row = rl + r * 16;
      int m = m0 + row;
      int k = k0 + klc;
      As[klc][row] = (m < M && k < K) ? A[(size_t)m * K + k] : 0.f;
      int n = n0 + row;
      Ws[klc][row] = (n < N && k < K) ? W[(size_t)n * K + k] : 0.f;
    }
    __syncthreads();
#pragma unroll
    for (int kk = 0; kk < 16; ++kk) {
      float4 a4 = *reinterpret_cast<const float4*>(&As[kk][ty * 4]);
      float4 w4 = *reinterpret_cast<const float4*>(&Ws[kk][tx * 4]);
      float av[4] = {a4.x, a4.y, a4.z, a4.w};
      float wv[4] = {w4.x, w4.y, w4.z, w4.w};
#pragma unroll
      for (int i = 0; i < 4; ++i)
#pragma unroll
        for (int j = 0; j < 4; ++j)
          acc[i][j] = fmaf(av[i], wv[j], acc[i][j]);
    }
    __syncthreads();
  }
#pragma unroll
  for (int i = 0; i < 4; ++i) {
    int m = m0 + ty * 4 + i;
    if (m >= M) continue;
#pragma unroll
    for (int j = 0; j < 4; ++j) {
      int n = n0 + tx * 4 + j;
      if (n >= N) continue;
      float v = acc[i][j];
      if (bias) v += bias[n];
      size_t idx = (size_t)m * N + n;
      if (MODE == 0) {
        C[idx] = v;
      } else if (MODE == 1) {
        float s = sigmoidf_(v);
        float em = s * aux1[idx];
        aux2[idx] = em * aux2[idx];
        aux3[idx] = em * aux3[idx];
      } else {
        float s = sigmoidf_(v);
        C[idx] = s * aux1[idx];
      }
    }
  }
}

// ---------------- prep: pack Whh (4 matrices) into f16 hi/lo MFMA A-fragments
// layout [mat 4][wave 8][gate 3][ktile 4][prec 2][lane 64][j 8] _Float16
// (scan uses prec=0 only this round; layout kept from verified r9)
__global__ __launch_bounds__(256) void prep_wfrag(
    const float* __restrict__ W0, const float* __restrict__ W1,
    const float* __restrict__ W2, const float* __restrict__ W3,
    _Float16* __restrict__ out) {
  int idx = blockIdx.x * 256 + threadIdx.x;
  if (idx >= 4 * 98304) return;
  int j = idx & 7;
  int lane = (idx >> 3) & 63;
  int prec = (idx >> 9) & 1;
  int k = (idx >> 10) & 3;
  int rest = idx >> 12;  // 0..95 = [mat][w][g]
  int mat = rest / 24;
  int wg = rest % 24;
  int w = wg / 3, g = wg % 3;
  const float* W = mat == 0 ? W0 : mat == 1 ? W1 : mat == 2 ? W2 : W3;
  int row = g * 128 + w * 16 + (lane & 15);
  int col = k * 32 + (lane >> 4) * 8 + j;
  float v = W[row * 128 + col];
  _Float16 hi = (_Float16)v;
  out[idx] = prec ? (_Float16)(v - (float)hi) : hi;
}

// ---------------- MFMA GRU scan: ONE block, all 16 batches as N=16.
// KEY FIX (r10): weights staged global -> LDS -> registers. LDS-sourced loads
// are NOT rematerializable (LDS written by other threads across a barrier), so
// the register allocator must keep the fragments live — unlike rounds 1-9
// where invariant global loads were "spilled" by re-issuing them in the loop.
// f16-only weights (12 MFMA/step). Two staging phases of 4 waves (48 KB LDS).
__global__ __launch_bounds__(512)
__attribute__((amdgpu_waves_per_eu(2, 2))) void gru_scan_mfma(
    const float* __restrict__ xg,    // [B, F, 384]
    const _Float16* __restrict__ wf, // this GRU's fragment pack
    const float* __restrict__ bhh,   // [384]
    const float* __restrict__ h0,    // [B, 128]
    float* __restrict__ hout,        // [B, F, 128]
    float* __restrict__ hlast,       // [B, 128]
    int F) {
  __shared__ __align__(16) _Float16 HT[2][16][136];  // [buf][batch][k+pad]
  __shared__ __align__(16) _Float16 WL[3072 * 8];    // 48 KB staging
  int tid = threadIdx.x;
  int wv = tid >> 6, l = tid & 63;
  int n = l & 15;       // batch (C col / B col)
  int rq = l >> 4;      // row-quad
  int rbase = wv * 16 + rq * 4;  // absolute h-row base (0..124)

  const f16x8* fbg = (const f16x8*)wf;
  f16x8* wl8 = (f16x8*)WL;
  f16x8 wfr[3][4];
#pragma unroll
  for (int p = 0; p < 2; ++p) {
    // stage hi-fragments of waves [4p, 4p+4) into WL
    for (int u = tid; u < 3072; u += 512) {
      int w = u / 768, rem = u - w * 768;
      int g = rem / 256, rem2 = rem - g * 256;
      int k = rem2 >> 6, ll = rem2 & 63;
      wl8[u] = fbg[((((4 * p + w) * 3 + g) * 4 + k) * 2 + 0) * 64 + ll];
    }
    __syncthreads();
    if ((wv >> 2) == p) {
      int w = wv & 3;
#pragma unroll
      for (int g = 0; g < 3; ++g)
#pragma unroll
        for (int k = 0; k < 4; ++k)
          wfr[g][k] = wl8[((w * 3 + g) * 4 + k) * 64 + l];
    }
    __syncthreads();
  }

  float bhr[4], bhz[4], bhn[4];
#pragma unroll
  for (int r = 0; r < 4; ++r) {
    bhr[r] = bhh[rbase + r];
    bhz[r] = bhh[128 + rbase + r];
    bhn[r] = bhh[256 + rbase + r];
  }
  float hp[4];
#pragma unroll
  for (int r = 0; r < 4; ++r) {
    hp[r] = h0[n * 128 + rbase + r];
    HT[0][n][rbase + r] = (_Float16)hp[r];
  }
  const float* xp = xg + ((size_t)n * F) * 384 + rbase;
  float* hq = hout + ((size_t)n * F) * 128 + rbase;
  // xg prefetch ring: slots for t (a) and t+1 (b)
  v4f xra = *(const v4f*)(xp);
  v4f xza = *(const v4f*)(xp + 128);
  v4f xna = *(const v4f*)(xp + 256);
  const float* p1 = xp + (size_t)(F > 1 ? 1 : 0) * 384;
  v4f xrb = *(const v4f*)(p1);
  v4f xzb = *(const v4f*)(p1 + 128);
  v4f xnb = *(const v4f*)(p1 + 256);
  __syncthreads();

  int cur = 0;
  for (int t = 0; t < F; ++t) {
    const _Float16* hrow = &HT[cur][n][0];
    f16x8 b0 = *(const f16x8*)(hrow + rq * 8);
    f16x8 b1 = *(const f16x8*)(hrow + 32 + rq * 8);
    f16x8 b2 = *(const f16x8*)(hrow + 64 + rq * 8);
    f16x8 b3 = *(const f16x8*)(hrow + 96 + rq * 8);
    v4f xr = xra, xz = xza, xn = xna;
    xra = xrb; xza = xzb; xna = xnb;
    {
      int tp = (t + 2 < F) ? t + 2 : F - 1;
      const float* p2 = xp + (size_t)tp * 384;
      xrb = *(const v4f*)(p2);
      xzb = *(const v4f*)(p2 + 128);
      xnb = *(const v4f*)(p2 + 256);
    }
    v4f ar = {0.f, 0.f, 0.f, 0.f}, az = ar, an = ar;
#pragma unroll
    for (int k = 0; k < 4; ++k) {
      f16x8 bk = (k == 0) ? b0 : (k == 1) ? b1 : (k == 2) ? b2 : b3;
      ar = __builtin_amdgcn_mfma_f32_16x16x32_f16(wfr[0][k], bk, ar, 0, 0, 0);
      az = __builtin_amdgcn_mfma_f32_16x16x32_f16(wfr[1][k], bk, az, 0, 0, 0);
      an = __builtin_amdgcn_mfma_f32_16x16x32_f16(wfr[2][k], bk, an, 0, 0, 0);
    }
    int nxt = cur ^ 1;
    f16x4 hv;
    v4f ho;
#pragma unroll
    for (int r = 0; r < 4; ++r) {
      float rr = sigmoidf_(ar[r] + bhr[r] + xr[r]);
      float zz = sigmoidf_(az[r] + bhz[r] + xz[r]);
      float gn = an[r] + bhn[r];
      float nv = tanhf_(xn[r] + rr * gn);
      float hn = (1.f - zz) * nv + zz * hp[r];
      hp[r] = hn;
      hv[r] = (_Float16)hn;
      ho[r] = hn;
    }
    *(f16x4*)&HT[nxt][n][rbase] = hv;
    *(v4f*)(hq + (size_t)t * 128) = ho;
    __syncthreads();  // HT[nxt] writes complete; HT[cur] reads were earlier
    cur = nxt;
  }
#pragma unroll
  for (int r = 0; r < 4; ++r) hlast[n * 128 + rbase + r] = hp[r];
}

// ---------------- instant layernorm over channels (256)
__global__ __launch_bounds__(256) void ln_kernel(
    const float* __restrict__ enc, const float* __restrict__ gamma,
    const float* __restrict__ beta, float* __restrict__ out) {
  int row = blockIdx.x * 4 + (threadIdx.x >> 6);
  int lane = threadIdx.x & 63;
  const float* p = enc + (size_t)row * ENCn;
  float4 v = *reinterpret_cast<const float4*>(p + lane * 4);
  float s = v.x + v.y + v.z + v.w;
  float ss = v.x * v.x + v.y * v.y + v.z * v.z + v.w * v.w;
#pragma unroll
  for (int o = 32; o > 0; o >>= 1) {
    s += __shfl_down(s, o);
    ss += __shfl_down(ss, o);
  }
  s = __shfl(s, 0);
  ss = __shfl(ss, 0);
  float mean = s * (1.f / 256.f);
  float var = ss * (1.f / 256.f) - mean * mean;
  float rstd = rsqrtf(var + 1e-7f);
  float4 g4 = *reinterpret_cast<const float4*>(gamma + lane * 4);
  float4 b4 = *reinterpret_cast<const float4*>(beta + lane * 4);
  float4 o4;
  o4.x = (v.x - mean) * rstd * g4.x + b4.x;
  o4.y = (v.y - mean) * rstd * g4.y + b4.y;
  o4.z = (v.z - mean) * rstd * g4.z + b4.z;
  o4.w = (v.w - mean) * rstd * g4.w + b4.w;
  *reinterpret_cast<float4*>(out + (size_t)row * ENCn + lane * 4) = o4;
}

// ---------------- overlap-add
__global__ __launch_bounds__(256) void ola_kernel(const float* __restrict__ dec,
                                                  float* __restrict__ out) {
  int idx = blockIdx.x * 256 + threadIdx.x;  // b*T + n
  int b = idx >> 18;                          // T = 2^18
  int n = idx & (T_LEN - 1);
  int f0 = (n < 768) ? 0 : ((n - 768) >> 8);
  int f1 = min(n >> 8, F_FRAMES - 1);
  float s = 0.f;
  for (int f = f0; f <= f1; ++f)
    s += dec[((size_t)b * F_FRAMES + f) * 1024 + (n - (f << 8))];
  out[idx] = s;
}

extern "C" void kernel_launch(void* const* d_in, const int* in_sizes, int n_in,
                              void* d_out, int out_size, void* d_ws,
                              size_t ws_size, hipStream_t stream) {
  const float* x = (const float*)d_in[0];
  const float* in_st1 = (const float*)d_in[1];
  const float* in_st2 = (const float*)d_in[2];
  const float* s1_Wih1 = (const float*)d_in[3];
  const float* s1_Whh1 = (const float*)d_in[4];
  const float* s1_bih1 = (const float*)d_in[5];
  const float* s1_bhh1 = (const float*)d_in[6];
  const float* s1_Wih2 = (const float*)d_in[7];
  const float* s1_Whh2 = (const float*)d_in[8];
  const float* s1_bih2 = (const float*)d_in[9];
  const float* s1_bhh2 = (const float*)d_in[10];
  const float* s1_Wd = (const float*)d_in[11];
  const float* s1_bd = (const float*)d_in[12];
  const float* enc_W = (const float*)d_in[13];
  const float* gamma = (const float*)d_in[14];
  const float* beta = (const float*)d_in[15];
  const float* s2_Wih1 = (const float*)d_in[16];
  const float* s2_Whh1 = (const float*)d_in[17];
  const float* s2_bih1 = (const float*)d_in[18];
  const float* s2_bhh1 = (const float*)d_in[19];
  const float* s2_Wih2 = (const float*)d_in[20];
  const float* s2_Whh2 = (const float*)d_in[21];
  const float* s2_bih2 = (const float*)d_in[22];
  const float* s2_bhh2 = (const float*)d_in[23];
  const float* s2_Wd = (const float*)d_in[24];
  const float* s2_bd = (const float*)d_in[25];
  const float* dec_W = (const float*)d_in[26];

  float* out = (float*)d_out;
  float* st_out = out + (size_t)BATCH * T_LEN;  // [2,16,128] + [2,16,128]

  float* ws = (float*)d_ws;
  float* mag = ws;                              // BF*513
  float* cosp = mag + (size_t)BF * FREQn;       // BF*513 (-> est_re)
  float* sinp = cosp + (size_t)BF * FREQn;      // BF*513 (-> est_im)
  float* xg = sinp + (size_t)BF * FREQn;        // BF*384 (shared A/B gate buf)
  float* h1 = xg + (size_t)BF * 384;            // BF*128
  float* h2 = h1 + (size_t)BF * HID;            // BF*128
  float* ybuf = h2 + (size_t)BF * HID;          // BF*1024 (y1, then dec)
  float* enc = ybuf + (size_t)BF * 1024;        // BF*256
  float* encn = enc + (size_t)BF * ENCn;        // BF*256 (enc_norm, then est2)
  _Float16* wfrag = (_Float16*)(encn + (size_t)BF * ENCn);  // 4*98304 f16

  auto gg = [](int M, int N) { return dim3((N + 63) / 64, (M + 63) / 64); };

  // 0. pack all four Whh into MFMA fragment order (f16 hi/lo)
  prep_wfrag<<<1536, 256, 0, stream>>>(s1_Whh1, s1_Whh2, s2_Whh1, s2_Whh2,
                                       wfrag);
  // 1. STFT -> mag, cos, sin
  stft_kernel<<<BF, 256, 0, stream>>>(x, mag, cosp, sinp);
  // 2. sep1 GRU-a input gates
  gemm_nt<0><<<gg(BF, 384), 256, 0, stream>>>(mag, s1_Wih1, s1_bih1, xg, BF,
                                              384, FREQn, nullptr, nullptr,
                                              nullptr);
  // 3. scan a
  gru_scan_mfma<<<1, 512, 0, stream>>>(xg, wfrag + 0 * 98304, s1_bhh1, in_st1,
                                       h1, st_out, F_FRAMES);
  // 4. sep1 GRU-b input gates (xg consumed by step 3 -> reuse)
  gemm_nt<0><<<gg(BF, 384), 256, 0, stream>>>(h1, s1_Wih2, s1_bih2, xg, BF,
                                              384, HID, nullptr, nullptr,
                                              nullptr);
  // 5. scan b
  gru_scan_mfma<<<1, 512, 0, stream>>>(xg, wfrag + 1 * 98304, s1_bhh2,
                                       in_st1 + 2048, h2, st_out + 2048,
                                       F_FRAMES);
  // 6. mask1 dense + est spectrum (overwrites cosp/sinp)
  gemm_nt<1><<<gg(BF, FREQn), 256, 0, stream>>>(h2, s1_Wd, s1_bd, nullptr, BF,
                                                FREQn, HID, mag, cosp, sinp);
  // 7. iSTFT -> y1
  istft_kernel<<<BF, 256, 0, stream>>>(cosp, sinp, ybuf);
  // 8. encoder
  gemm_nt<0><<<gg(BF, ENCn), 256, 0, stream>>>(ybuf, enc_W, nullptr, enc, BF,
                                               ENCn, 1024, nullptr, nullptr,
                                               nullptr);
  // 9. instant LN
  ln_kernel<<<BF / 4, 256, 0, stream>>>(enc, gamma, beta, encn);
  // 10. sep2 GRU-a input gates
  gemm_nt<0><<<gg(BF, 384), 256, 0, stream>>>(encn, s2_Wih1, s2_bih1, xg, BF,
                                              384, ENCn, nullptr, nullptr,
                                              nullptr);
  // 11. scan 2a
  gru_scan_mfma<<<1, 512, 0, stream>>>(xg, wfrag + 2 * 98304, s2_bhh1, in_st2,
                                       h1, st_out + 4096, F_FRAMES);
  // 12. sep2 GRU-b input gates
  gemm_nt<0><<<gg(BF, 384), 256, 0, stream>>>(h1, s2_Wih2, s2_bih2, xg, BF,
                                              384, HID, nullptr, nullptr,
                                              nullptr);
  // 13. scan 2b
  gru_scan_mfma<<<1, 512, 0, stream>>>(xg, wfrag + 3 * 98304, s2_bhh2,
                                       in_st2 + 2048, h2, st_out + 6144,
                                       F_FRAMES);
  // 14. mask2 -> est2 (reads enc, writes encn)
  gemm_nt<2><<<gg(BF, ENCn), 256, 0, stream>>>(h2, s2_Wd, s2_bd, encn, BF,
                                               ENCn, HID, enc, nullptr,
                                               nullptr);
  // 15. decoder (reuses ybuf)
  gemm_nt<0><<<gg(BF, 1024), 256, 0, stream>>>(encn, dec_W, nullptr, ybuf, BF,
                                               1024, ENCn, nullptr, nullptr,
                                               nullptr);
  // 16. overlap-add
  ola_kernel<<<(BATCH * T_LEN) / 256, 256, 0, stream>>>(ybuf, out);
}

// Round 11
// 5296.987 us; speedup vs baseline: 1.4817x; 1.0279x over previous
//
#include <hip/hip_runtime.h>
#include <math.h>

#define F_FRAMES 1021
#define BATCH 16
#define T_LEN 262144
#define FREQn 513
#define HID 128
#define ENCn 256
#define BF (BATCH * F_FRAMES)  // 16336

typedef float v4f __attribute__((ext_vector_type(4)));
typedef _Float16 f16x8 __attribute__((ext_vector_type(8)));
typedef _Float16 f16x4 __attribute__((ext_vector_type(4)));

__device__ __forceinline__ float sigmoidf_(float x) {
  return 1.f / (1.f + __expf(-x));
}
__device__ __forceinline__ float tanhf_(float x) {
  return 1.f - 2.f / (__expf(2.f * x) + 1.f);
}

// ---------------- STFT: frame + window + rfft(1024) -> mag, cos(phase), sin(phase)
__global__ __launch_bounds__(256) void stft_kernel(
    const float* __restrict__ x, float* __restrict__ mag,
    float* __restrict__ cosp, float* __restrict__ sinp) {
  __shared__ float zr[512], zi[512];
  int bf = blockIdx.x;
  int b = bf / F_FRAMES;
  int f = bf - b * F_FRAMES;
  const float* xb = x + (size_t)b * T_LEN + (size_t)f * 256;
  int tid = threadIdx.x;
  const float wstep = 6.28318530717958647692f / 1024.f;
#pragma unroll
  for (int u = 0; u < 2; ++u) {
    int j = tid + u * 256;
    int n = __brev((unsigned)j) >> 23;  // 9-bit bit-reverse
    float x0 = xb[2 * n] * (0.5f - 0.5f * __cosf((float)(2 * n) * wstep));
    float x1 = xb[2 * n + 1] * (0.5f - 0.5f * __cosf((float)(2 * n + 1) * wstep));
    zr[j] = x0;
    zi[j] = x1;
  }
  __syncthreads();
#pragma unroll
  for (int s = 1; s <= 9; ++s) {
    int half = 1 << (s - 1);
    int t = tid & (half - 1);
    int g = tid >> (s - 1);
    int pos = (g << s) + t;
    float ang = (float)t * (3.14159265358979323846f / (float)half);
    float sn, cs;
    __sincosf(ang, &sn, &cs);
    float wr = cs, wi = -sn;
    float ar = zr[pos], ai = zi[pos];
    float br = zr[pos + half], bi = zi[pos + half];
    float tr = wr * br - wi * bi;
    float ti = wr * bi + wi * br;
    zr[pos] = ar + tr;
    zi[pos] = ai + ti;
    zr[pos + half] = ar - tr;
    zi[pos + half] = ai - ti;
    __syncthreads();
  }
  const float eps = 1.1920928955078125e-07f;
  for (int k = tid; k < 513; k += 256) {
    int ka = k & 511;
    int kb = (512 - k) & 511;
    float zar = zr[ka], zai = zi[ka];
    float zbr = zr[kb], zbi = zi[kb];
    float Zer = 0.5f * (zar + zbr);
    float Zei = 0.5f * (zai - zbi);
    float Zor = 0.5f * (zai + zbi);
    float Zoi = -0.5f * (zar - zbr);
    float ang = (float)k * (3.14159265358979323846f / 512.f);
    float sn, cs;
    __sincosf(ang, &sn, &cs);
    float Wr = cs, Wi = -sn;
    float re = Zer + Wr * Zor - Wi * Zoi;
    float im = Zei + Wr * Zoi + Wi * Zor;
    size_t idx = (size_t)bf * FREQn + k;
    float p2 = re * re + im * im;
    mag[idx] = sqrtf(fmaxf(p2, eps));
    float rr = re + eps, ii = im + eps;
    float inv = rsqrtf(rr * rr + ii * ii);
    cosp[idx] = rr * inv;
    sinp[idx] = ii * inv;
  }
}

// ---------------- iSTFT: est spectrum -> irfft(1024) frames
__global__ __launch_bounds__(256) void istft_kernel(
    const float* __restrict__ er, const float* __restrict__ ei,
    float* __restrict__ y) {
  __shared__ float xr[513], xi[513];
  __shared__ float zr[512], zi[512];
  int bf = blockIdx.x;
  int tid = threadIdx.x;
  for (int k = tid; k < 513; k += 256) {
    size_t idx = (size_t)bf * FREQn + k;
    xr[k] = er[idx];
    float v = ei[idx];
    xi[k] = (k == 0 || k == 512) ? 0.f : v;  // pocketfft c2r ignores DC/Nyquist imag
  }
  __syncthreads();
#pragma unroll
  for (int u = 0; u < 2; ++u) {
    int k = tid + u * 256;  // 0..511
    int kk = 512 - k;
    float Xkr = xr[k], Xki = xi[k];
    float Xbr = xr[kk], Xbi = xi[kk];
    float Zer = 0.5f * (Xkr + Xbr);
    float Zei = 0.5f * (Xki - Xbi);
    float Vr = 0.5f * (Xkr - Xbr);
    float Vi = 0.5f * (Xki + Xbi);
    float ang = (float)k * (3.14159265358979323846f / 512.f);
    float sn, cs;
    __sincosf(ang, &sn, &cs);
    float Zor = cs * Vr - sn * Vi;  // e^{+i pi k/512} * V
    float Zoi = cs * Vi + sn * Vr;
    float Rr = Zer - Zoi;  // Z = Ze + i*Zo
    float Ri = Zei + Zor;
    int d = __brev((unsigned)k) >> 23;
    zr[d] = Rr;
    zi[d] = Ri;
  }
  __syncthreads();
#pragma unroll
  for (int s = 1; s <= 9; ++s) {
    int half = 1 << (s - 1);
    int t = tid & (half - 1);
    int g = tid >> (s - 1);
    int pos = (g << s) + t;
    float ang = (float)t * (3.14159265358979323846f / (float)half);
    float sn, cs;
    __sincosf(ang, &sn, &cs);
    float wr = cs, wi = sn;  // conjugate twiddles => unnormalized IDFT
    float ar = zr[pos], ai = zi[pos];
    float br = zr[pos + half], bi = zi[pos + half];
    float tr = wr * br - wi * bi;
    float ti = wr * bi + wi * br;
    zr[pos] = ar + tr;
    zi[pos] = ai + ti;
    zr[pos + half] = ar - tr;
    zi[pos + half] = ai - ti;
    __syncthreads();
  }
  const float sc = 1.f / 512.f;
  float2* y2 = (float2*)(y + (size_t)bf * 1024);
#pragma unroll
  for (int u = 0; u < 2; ++u) {
    int n = tid + u * 256;
    y2[n] = make_float2(zr[n] * sc, zi[n] * sc);
  }
}

// ---------------- generic fp32 GEMM: C[M,N] = A[M,K] @ W[N,K]^T (+bias)(+epilogue)
template <int MODE>
__global__ __launch_bounds__(256) void gemm_nt(
    const float* __restrict__ A, const float* __restrict__ W,
    const float* __restrict__ bias, float* __restrict__ C, int M, int N, int K,
    const float* __restrict__ aux1, float* __restrict__ aux2,
    float* __restrict__ aux3) {
  __shared__ float As[16][68];
  __shared__ float Ws[16][68];
  int tid = threadIdx.x;
  int tx = tid & 15, ty = tid >> 4;
  int m0 = blockIdx.y * 64, n0 = blockIdx.x * 64;
  float acc[4][4] = {};
  int klc = tid & 15;
  int rl = tid >> 4;
  for (int k0 = 0; k0 < K; k0 += 16) {
#pragma unroll
    for (int r = 0; r < 4; ++r) {
      int row = rl + r * 16;
      int m = m0 + row;
      int k = k0 + klc;
      As[klc][row] = (m < M && k < K) ? A[(size_t)m * K + k] : 0.f;
      int n = n0 + row;
      Ws[klc][row] = (n < N && k < K) ? W[(size_t)n * K + k] : 0.f;
    }
    __syncthreads();
#pragma unroll
    for (int kk = 0; kk < 16; ++kk) {
      float4 a4 = *reinterpret_cast<const float4*>(&As[kk][ty * 4]);
      float4 w4 = *reinterpret_cast<const float4*>(&Ws[kk][tx * 4]);
      float av[4] = {a4.x, a4.y, a4.z, a4.w};
      float wv[4] = {w4.x, w4.y, w4.z, w4.w};
#pragma unroll
      for (int i = 0; i < 4; ++i)
#pragma unroll
        for (int j = 0; j < 4; ++j)
          acc[i][j] = fmaf(av[i], wv[j], acc[i][j]);
    }
    __syncthreads();
  }
#pragma unroll
  for (int i = 0; i < 4; ++i) {
    int m = m0 + ty * 4 + i;
    if (m >= M) continue;
#pragma unroll
    for (int j = 0; j < 4; ++j) {
      int n = n0 + tx * 4 + j;
      if (n >= N) continue;
      float v = acc[i][j];
      if (bias) v += bias[n];
      size_t idx = (size_t)m * N + n;
      if (MODE == 0) {
        C[idx] = v;
      } else if (MODE == 1) {
        float s = sigmoidf_(v);
        float em = s * aux1[idx];
        aux2[idx] = em * aux2[idx];
        aux3[idx] = em * aux3[idx];
      } else {
        float s = sigmoidf_(v);
        C[idx] = s * aux1[idx];
      }
    }
  }
}

// ---------------- prep: pack Whh (4 matrices) into f16 hi/lo MFMA A-fragments
// layout [mat 4][wave 8][gate 3][ktile 4][prec 2][lane 64][j 8] _Float16
// (scan uses prec=0 only; layout kept from verified r9)
__global__ __launch_bounds__(256) void prep_wfrag(
    const float* __restrict__ W0, const float* __restrict__ W1,
    const float* __restrict__ W2, const float* __restrict__ W3,
    _Float16* __restrict__ out) {
  int idx = blockIdx.x * 256 + threadIdx.x;
  if (idx >= 4 * 98304) return;
  int j = idx & 7;
  int lane = (idx >> 3) & 63;
  int prec = (idx >> 9) & 1;
  int k = (idx >> 10) & 3;
  int rest = idx >> 12;  // 0..95 = [mat][w][g]
  int mat = rest / 24;
  int wg = rest % 24;
  int w = wg / 3, g = wg % 3;
  const float* W = mat == 0 ? W0 : mat == 1 ? W1 : mat == 2 ? W2 : W3;
  int row = g * 128 + w * 16 + (lane & 15);
  int col = k * 32 + (lane >> 4) * 8 + j;
  float v = W[row * 128 + col];
  _Float16 hi = (_Float16)v;
  out[idx] = prec ? (_Float16)(v - (float)hi) : hi;
}

// ---------------- MFMA GRU scan: ONE block, all 16 batches as N=16.
// r10: weights staged global->LDS->registers (fragments stay in VGPRs).
// r11 FIX: replace in-loop __syncthreads() (which emits s_waitcnt vmcnt(0)
// lgkmcnt(0) -> drains the xg prefetch + hout store EVERY step, ~1500cy) with
// `s_waitcnt lgkmcnt(0)` + raw s_barrier. LDS ordering for HT is preserved
// (ds_write drained before barrier); global loads/stores stay in flight
// across the barrier so the t+2 prefetch ring actually pipelines.
__global__ __launch_bounds__(512)
__attribute__((amdgpu_waves_per_eu(2, 2))) void gru_scan_mfma(
    const float* __restrict__ xg,    // [B, F, 384]
    const _Float16* __restrict__ wf, // this GRU's fragment pack
    const float* __restrict__ bhh,   // [384]
    const float* __restrict__ h0,    // [B, 128]
    float* __restrict__ hout,        // [B, F, 128]
    float* __restrict__ hlast,       // [B, 128]
    int F) {
  __shared__ __align__(16) _Float16 HT[2][16][136];  // [buf][batch][k+pad]
  __shared__ __align__(16) _Float16 WL[3072 * 8];    // 48 KB staging
  int tid = threadIdx.x;
  int wv = tid >> 6, l = tid & 63;
  int n = l & 15;       // batch (C col / B col)
  int rq = l >> 4;      // row-quad
  int rbase = wv * 16 + rq * 4;  // absolute h-row base (0..124)

  const f16x8* fbg = (const f16x8*)wf;
  f16x8* wl8 = (f16x8*)WL;
  f16x8 wfr[3][4];
#pragma unroll
  for (int p = 0; p < 2; ++p) {
    // stage hi-fragments of waves [4p, 4p+4) into WL
    for (int u = tid; u < 3072; u += 512) {
      int w = u / 768, rem = u - w * 768;
      int g = rem / 256, rem2 = rem - g * 256;
      int k = rem2 >> 6, ll = rem2 & 63;
      wl8[u] = fbg[((((4 * p + w) * 3 + g) * 4 + k) * 2 + 0) * 64 + ll];
    }
    __syncthreads();
    if ((wv >> 2) == p) {
      int w = wv & 3;
#pragma unroll
      for (int g = 0; g < 3; ++g)
#pragma unroll
        for (int k = 0; k < 4; ++k)
          wfr[g][k] = wl8[((w * 3 + g) * 4 + k) * 64 + l];
    }
    __syncthreads();
  }

  float bhr[4], bhz[4], bhn[4];
#pragma unroll
  for (int r = 0; r < 4; ++r) {
    bhr[r] = bhh[rbase + r];
    bhz[r] = bhh[128 + rbase + r];
    bhn[r] = bhh[256 + rbase + r];
  }
  float hp[4];
#pragma unroll
  for (int r = 0; r < 4; ++r) {
    hp[r] = h0[n * 128 + rbase + r];
    HT[0][n][rbase + r] = (_Float16)hp[r];
  }
  const float* xp = xg + ((size_t)n * F) * 384 + rbase;
  float* hq = hout + ((size_t)n * F) * 128 + rbase;
  // xg prefetch ring: slots for t (a) and t+1 (b)
  v4f xra = *(const v4f*)(xp);
  v4f xza = *(const v4f*)(xp + 128);
  v4f xna = *(const v4f*)(xp + 256);
  const float* p1 = xp + (size_t)(F > 1 ? 1 : 0) * 384;
  v4f xrb = *(const v4f*)(p1);
  v4f xzb = *(const v4f*)(p1 + 128);
  v4f xnb = *(const v4f*)(p1 + 256);
  __syncthreads();

  int cur = 0;
  for (int t = 0; t < F; ++t) {
    const _Float16* hrow = &HT[cur][n][0];
    f16x8 b0 = *(const f16x8*)(hrow + rq * 8);
    f16x8 b1 = *(const f16x8*)(hrow + 32 + rq * 8);
    f16x8 b2 = *(const f16x8*)(hrow + 64 + rq * 8);
    f16x8 b3 = *(const f16x8*)(hrow + 96 + rq * 8);
    v4f xr = xra, xz = xza, xn = xna;
    xra = xrb; xza = xzb; xna = xnb;
    {
      int tp = (t + 2 < F) ? t + 2 : F - 1;
      const float* p2 = xp + (size_t)tp * 384;
      xrb = *(const v4f*)(p2);
      xzb = *(const v4f*)(p2 + 128);
      xnb = *(const v4f*)(p2 + 256);
    }
    v4f ar = {0.f, 0.f, 0.f, 0.f}, az = ar, an = ar;
#pragma unroll
    for (int k = 0; k < 4; ++k) {
      f16x8 bk = (k == 0) ? b0 : (k == 1) ? b1 : (k == 2) ? b2 : b3;
      ar = __builtin_amdgcn_mfma_f32_16x16x32_f16(wfr[0][k], bk, ar, 0, 0, 0);
      az = __builtin_amdgcn_mfma_f32_16x16x32_f16(wfr[1][k], bk, az, 0, 0, 0);
      an = __builtin_amdgcn_mfma_f32_16x16x32_f16(wfr[2][k], bk, an, 0, 0, 0);
    }
    int nxt = cur ^ 1;
    f16x4 hv;
    v4f ho;
#pragma unroll
    for (int r = 0; r < 4; ++r) {
      float rr = sigmoidf_(ar[r] + bhr[r] + xr[r]);
      float zz = sigmoidf_(az[r] + bhz[r] + xz[r]);
      float gn = an[r] + bhn[r];
      float nv = tanhf_(xn[r] + rr * gn);
      float hn = (1.f - zz) * nv + zz * hp[r];
      hp[r] = hn;
      hv[r] = (_Float16)hn;
      ho[r] = hn;
    }
    *(f16x4*)&HT[nxt][n][rbase] = hv;
    *(v4f*)(hq + (size_t)t * 128) = ho;
    // LDS-only fence + raw barrier: HT[nxt] ds_write drained for cross-wave
    // visibility; global (xg prefetch / hout store) stays in flight.
    asm volatile("s_waitcnt lgkmcnt(0)" ::: "memory");
    __builtin_amdgcn_s_barrier();
    cur = nxt;
  }
#pragma unroll
  for (int r = 0; r < 4; ++r) hlast[n * 128 + rbase + r] = hp[r];
}

// ---------------- instant layernorm over channels (256)
__global__ __launch_bounds__(256) void ln_kernel(
    const float* __restrict__ enc, const float* __restrict__ gamma,
    const float* __restrict__ beta, float* __restrict__ out) {
  int row = blockIdx.x * 4 + (threadIdx.x >> 6);
  int lane = threadIdx.x & 63;
  const float* p = enc + (size_t)row * ENCn;
  float4 v = *reinterpret_cast<const float4*>(p + lane * 4);
  float s = v.x + v.y + v.z + v.w;
  float ss = v.x * v.x + v.y * v.y + v.z * v.z + v.w * v.w;
#pragma unroll
  for (int o = 32; o > 0; o >>= 1) {
    s += __shfl_down(s, o);
    ss += __shfl_down(ss, o);
  }
  s = __shfl(s, 0);
  ss = __shfl(ss, 0);
  float mean = s * (1.f / 256.f);
  float var = ss * (1.f / 256.f) - mean * mean;
  float rstd = rsqrtf(var + 1e-7f);
  float4 g4 = *reinterpret_cast<const float4*>(gamma + lane * 4);
  float4 b4 = *reinterpret_cast<const float4*>(beta + lane * 4);
  float4 o4;
  o4.x = (v.x - mean) * rstd * g4.x + b4.x;
  o4.y = (v.y - mean) * rstd * g4.y + b4.y;
  o4.z = (v.z - mean) * rstd * g4.z + b4.z;
  o4.w = (v.w - mean) * rstd * g4.w + b4.w;
  *reinterpret_cast<float4*>(out + (size_t)row * ENCn + lane * 4) = o4;
}

// ---------------- overlap-add
__global__ __launch_bounds__(256) void ola_kernel(const float* __restrict__ dec,
                                                  float* __restrict__ out) {
  int idx = blockIdx.x * 256 + threadIdx.x;  // b*T + n
  int b = idx >> 18;                          // T = 2^18
  int n = idx & (T_LEN - 1);
  int f0 = (n < 768) ? 0 : ((n - 768) >> 8);
  int f1 = min(n >> 8, F_FRAMES - 1);
  float s = 0.f;
  for (int f = f0; f <= f1; ++f)
    s += dec[((size_t)b * F_FRAMES + f) * 1024 + (n - (f << 8))];
  out[idx] = s;
}

extern "C" void kernel_launch(void* const* d_in, const int* in_sizes, int n_in,
                              void* d_out, int out_size, void* d_ws,
                              size_t ws_size, hipStream_t stream) {
  const float* x = (const float*)d_in[0];
  const float* in_st1 = (const float*)d_in[1];
  const float* in_st2 = (const float*)d_in[2];
  const float* s1_Wih1 = (const float*)d_in[3];
  const float* s1_Whh1 = (const float*)d_in[4];
  const float* s1_bih1 = (const float*)d_in[5];
  const float* s1_bhh1 = (const float*)d_in[6];
  const float* s1_Wih2 = (const float*)d_in[7];
  const float* s1_Whh2 = (const float*)d_in[8];
  const float* s1_bih2 = (const float*)d_in[9];
  const float* s1_bhh2 = (const float*)d_in[10];
  const float* s1_Wd = (const float*)d_in[11];
  const float* s1_bd = (const float*)d_in[12];
  const float* enc_W = (const float*)d_in[13];
  const float* gamma = (const float*)d_in[14];
  const float* beta = (const float*)d_in[15];
  const float* s2_Wih1 = (const float*)d_in[16];
  const float* s2_Whh1 = (const float*)d_in[17];
  const float* s2_bih1 = (const float*)d_in[18];
  const float* s2_bhh1 = (const float*)d_in[19];
  const float* s2_Wih2 = (const float*)d_in[20];
  const float* s2_Whh2 = (const float*)d_in[21];
  const float* s2_bih2 = (const float*)d_in[22];
  const float* s2_bhh2 = (const float*)d_in[23];
  const float* s2_Wd = (const float*)d_in[24];
  const float* s2_bd = (const float*)d_in[25];
  const float* dec_W = (const float*)d_in[26];

  float* out = (float*)d_out;
  float* st_out = out + (size_t)BATCH * T_LEN;  // [2,16,128] + [2,16,128]

  float* ws = (float*)d_ws;
  float* mag = ws;                              // BF*513
  float* cosp = mag + (size_t)BF * FREQn;       // BF*513 (-> est_re)
  float* sinp = cosp + (size_t)BF * FREQn;      // BF*513 (-> est_im)
  float* xg = sinp + (size_t)BF * FREQn;        // BF*384 (shared A/B gate buf)
  float* h1 = xg + (size_t)BF * 384;            // BF*128
  float* h2 = h1 + (size_t)BF * HID;            // BF*128
  float* ybuf = h2 + (size_t)BF * HID;          // BF*1024 (y1, then dec)
  float* enc = ybuf + (size_t)BF * 1024;        // BF*256
  float* encn = enc + (size_t)BF * ENCn;        // BF*256 (enc_norm, then est2)
  _Float16* wfrag = (_Float16*)(encn + (size_t)BF * ENCn);  // 4*98304 f16

  auto gg = [](int M, int N) { return dim3((N + 63) / 64, (M + 63) / 64); };

  // 0. pack all four Whh into MFMA fragment order (f16 hi/lo)
  prep_wfrag<<<1536, 256, 0, stream>>>(s1_Whh1, s1_Whh2, s2_Whh1, s2_Whh2,
                                       wfrag);
  // 1. STFT -> mag, cos, sin
  stft_kernel<<<BF, 256, 0, stream>>>(x, mag, cosp, sinp);
  // 2. sep1 GRU-a input gates
  gemm_nt<0><<<gg(BF, 384), 256, 0, stream>>>(mag, s1_Wih1, s1_bih1, xg, BF,
                                              384, FREQn, nullptr, nullptr,
                                              nullptr);
  // 3. scan a
  gru_scan_mfma<<<1, 512, 0, stream>>>(xg, wfrag + 0 * 98304, s1_bhh1, in_st1,
                                       h1, st_out, F_FRAMES);
  // 4. sep1 GRU-b input gates (xg consumed by step 3 -> reuse)
  gemm_nt<0><<<gg(BF, 384), 256, 0, stream>>>(h1, s1_Wih2, s1_bih2, xg, BF,
                                              384, HID, nullptr, nullptr,
                                              nullptr);
  // 5. scan b
  gru_scan_mfma<<<1, 512, 0, stream>>>(xg, wfrag + 1 * 98304, s1_bhh2,
                                       in_st1 + 2048, h2, st_out + 2048,
                                       F_FRAMES);
  // 6. mask1 dense + est spectrum (overwrites cosp/sinp)
  gemm_nt<1><<<gg(BF, FREQn), 256, 0, stream>>>(h2, s1_Wd, s1_bd, nullptr, BF,
                                                FREQn, HID, mag, cosp, sinp);
  // 7. iSTFT -> y1
  istft_kernel<<<BF, 256, 0, stream>>>(cosp, sinp, ybuf);
  // 8. encoder
  gemm_nt<0><<<gg(BF, ENCn), 256, 0, stream>>>(ybuf, enc_W, nullptr, enc, BF,
                                               ENCn, 1024, nullptr, nullptr,
                                               nullptr);
  // 9. instant LN
  ln_kernel<<<BF / 4, 256, 0, stream>>>(enc, gamma, beta, encn);
  // 10. sep2 GRU-a input gates
  gemm_nt<0><<<gg(BF, 384), 256, 0, stream>>>(encn, s2_Wih1, s2_bih1, xg, BF,
                                              384, ENCn, nullptr, nullptr,
                                              nullptr);
  // 11. scan 2a
  gru_scan_mfma<<<1, 512, 0, stream>>>(xg, wfrag + 2 * 98304, s2_bhh1, in_st2,
                                       h1, st_out + 4096, F_FRAMES);
  // 12. sep2 GRU-b input gates
  gemm_nt<0><<<gg(BF, 384), 256, 0, stream>>>(h1, s2_Wih2, s2_bih2, xg, BF,
                                              384, HID, nullptr, nullptr,
                                              nullptr);
  // 13. scan 2b
  gru_scan_mfma<<<1, 512, 0, stream>>>(xg, wfrag + 3 * 98304, s2_bhh2,
                                       in_st2 + 2048, h2, st_out + 6144,
                                       F_FRAMES);
  // 14. mask2 -> est2 (reads enc, writes encn)
  gemm_nt<2><<<gg(BF, ENCn), 256, 0, stream>>>(h2, s2_Wd, s2_bd, encn, BF,
                                               ENCn, HID, enc, nullptr,
                                               nullptr);
  // 15. decoder (reuses ybuf)
  gemm_nt<0><<<gg(BF, 1024), 256, 0, stream>>>(encn, dec_W, nullptr, ybuf, BF,
                                               1024, ENCn, nullptr, nullptr,
                                               nullptr);
  // 16. overlap-add
  ola_kernel<<<(BATCH * T_LEN) / 256, 256, 0, stream>>>(ybuf, out);
}